// Round 14
// baseline (97.972 us; speedup 1.0000x reference)
//
#include <hip/hip_runtime.h>
#include <hip/hip_bf16.h>

// Problem constants
#define NB 32
#define T_LEN 8192
#define CKC 256
#define UQ 128
#define NCHUNK 64
#define ROWS_PER_CHUNK 128   // T_LEN / NCHUNK
#define STEP 16
#define NPAIRS 4             // pairs of 16-row tiles; 32 rows per barrier window
#define PART_STRIDE 258
#define FIXED_MAX 25.0f      // scores provably < 25; exp(st-25) in [e^-60, e^-2]

typedef short short8 __attribute__((ext_vector_type(8)));
typedef float f32x4 __attribute__((ext_vector_type(4)));
typedef unsigned short ushort4_t __attribute__((ext_vector_type(4)));

__device__ __forceinline__ unsigned short f2bf(float x) {
  union { float f; unsigned u; } un; un.f = x;
  unsigned r = un.u + 0x7FFFu + ((un.u >> 16) & 1u);
  return (unsigned short)(r >> 16);
}
__device__ __forceinline__ float bf2f(unsigned short h) {
  union { unsigned u; float f; } un; un.u = ((unsigned)h) << 16;
  return un.f;
}
__device__ __forceinline__ float fast_tanh(float x) {
  float e = __expf(2.0f * x);
  return 1.0f - 2.0f / (e + 1.0f);   // saturates correctly for |x| large
}
__device__ __forceinline__ ushort4_t pack_bf16x4(f32x4 x) {
  union { __hip_bfloat162 h; unsigned short u[2]; } a, b;
  a.h = __float22bfloat162_rn(make_float2(x[0], x[1]));
  b.h = __float22bfloat162_rn(make_float2(x[2], x[3]));
  ushort4_t r; r[0] = a.u[0]; r[1] = a.u[1]; r[2] = b.u[0]; r[3] = b.u[1];
  return r;
}
// Publishing barrier: waits only this wave's LDS ops, does NOT drain vmcnt.
__device__ __forceinline__ void barrier_lgkm() {
  asm volatile("s_waitcnt lgkmcnt(0)" ::: "memory");
  __builtin_amdgcn_s_barrier();
}
// Pure-VALU 16-lane reduction step (DPP row_shl, 0-fill).
template <int N>
__device__ __forceinline__ float row_shl_add(float x) {
  int y = __builtin_amdgcn_update_dpp(0, __float_as_int(x),
                                      0x100 | N, 0xf, 0xf, true);
  return x + __int_as_float(y);
}
__device__ __forceinline__ float hsum4(f32x4 x) {
  return (x[0] + x[1]) + (x[2] + x[3]);
}

// ---------------------------------------------------------------------------
// Kernel 0 (fused prep):
__global__ void prep_kernel(const float* __restrict__ query,
                            const float* __restrict__ w_conv,
                            const float* __restrict__ w_q,
                            const float* __restrict__ bvec,
                            const float* __restrict__ w_k,
                            float* __restrict__ qpb,
                            unsigned short* __restrict__ wkT_hi) {
  const int tid = threadIdx.x;
  if (blockIdx.x >= NB) {
    const int c = blockIdx.x - NB;   // 0..255
    if (tid < UQ) wkT_hi[tid * CKC + c] = f2bf(w_k[c * UQ + tid]);
    return;
  }
  __shared__ float qr[256];
  __shared__ float qv[256];
  const int n = blockIdx.x;
  qr[tid] = query[n * 256 + tid];
  __syncthreads();
  float acc = 0.f;
  const f32x4* wrow = (const f32x4*)(w_conv + (size_t)tid * 256);
  const f32x4* q4 = (const f32x4*)qr;
#pragma unroll 8
  for (int i = 0; i < 64; ++i) {
    f32x4 wv4 = wrow[i];
    f32x4 qq = q4[i];
    acc += wv4[0] * qq[0] + wv4[1] * qq[1] + wv4[2] * qq[2] + wv4[3] * qq[3];
  }
  qv[tid] = acc;
  __syncthreads();
  if (tid < UQ) {
    float a2 = bvec[tid];
#pragma unroll 4
    for (int c = 0; c < 256; ++c) a2 += qv[c] * w_q[c * UQ + tid];
    qpb[n * UQ + tid] = a2;
  }
}

// ---------------------------------------------------------------------------
// Kernel 1: fused kernel, PAIR-processed (R13 structure) + s_setprio around
// the ds_read+MFMA cluster (T5: pays when the co-resident block is in a
// different phase) + qpb folded into the MFMA C-initializer.
__global__ __launch_bounds__(512, 2)
void fused_attn_kernel(const float* __restrict__ key,
                       const float* __restrict__ gumbel,
                       const float* __restrict__ v,
                       const float* __restrict__ qpb,
                       const unsigned short* __restrict__ wkT_hi,
                       float* __restrict__ part,
                       float* __restrict__ out_align) {
  __shared__ __align__(16) unsigned short ldsHi[2][2][STEP * CKC]; // 4 x 8KB
  __shared__ __align__(16) float spart_t[2][2][STEP][8]; // [pair][tile][row][wv]
  __shared__ __align__(16) float ctx8[8][256];           // epilogue reduce
  __shared__ float gbuf[ROWS_PER_CHUNK];
  __shared__ float lred[8];

  const int tid = threadIdx.x;
  const int lane = tid & 63;
  const int wv = tid >> 6;  // 0..7
  const int bid = blockIdx.x;
  const int n = bid >> 6;
  const int chunk = bid & 63;
  const int t0 = chunk * ROWS_PER_CHUNK;

  // gumbel chunk -> LDS (published by the first in-loop barrier)
  if (tid < ROWS_PER_CHUNK) gbuf[tid] = gumbel[n * T_LEN + t0 + tid];

  // lane-fixed u (C/D col = lane&15): D[key_row][u]
  const int u = wv * 16 + (lane & 15);
  const float qpb_u = qpb[n * UQ + u];
  const float v_u = v[u];

  // B fragments (w_k) in registers: k = kt*32 + 8*(lane>>4) + j, col = u
  short8 bhi[8];
  {
    const int koff = (lane >> 4) * 8;
#pragma unroll
    for (int kt = 0; kt < 8; ++kt)
      bhi[kt] = *(const short8*)(wkT_hi + (size_t)u * CKC + kt * 32 + koff);
  }

  // staging geometry (tile-local): rows wv, wv+8; float4 cols c40..c40+3
  const int c40 = (tid & 63) << 2;
  const unsigned off0 = ((unsigned)(wv * 512 + c40 * 2)) ^ ((unsigned)wv << 4);
  const unsigned off1 = ((unsigned)((wv + 8) * 512 + c40 * 2)) ^ ((unsigned)wv << 4);

  // A-fragment (key) read offsets (tile-local)
  const int ar = lane & 15;
  const unsigned axor = ((unsigned)(ar & 7)) << 4;
  const unsigned abase = (unsigned)(ar * 512 + (lane >> 4) * 16);

  const float* keyN = key + (size_t)n * T_LEN * CKC;

  // cur = pair pr rows: [tileA row wv, tileA row wv+8, tileB row wv, tileB wv+8]
  f32x4 cur[4];
  cur[0] = *(const f32x4*)(keyN + (size_t)(t0 + wv) * CKC + c40);
  cur[1] = *(const f32x4*)(keyN + (size_t)(t0 + wv + 8) * CKC + c40);
  cur[2] = *(const f32x4*)(keyN + (size_t)(t0 + 16 + wv) * CKC + c40);
  cur[3] = *(const f32x4*)(keyN + (size_t)(t0 + 16 + wv + 8) * CKC + c40);

  ushort4_t pv[4];                    // packed bf16 rows of pair pr-1
  float l_acc = 0.0f;
  f32x4 acc0 = {0.f, 0.f, 0.f, 0.f};  // context accum, row-slot wv
  f32x4 acc1 = {0.f, 0.f, 0.f, 0.f};  // context accum, row-slot wv+8

#pragma unroll
  for (int pr = 0; pr < NPAIRS; ++pr) {
    const int p = pr & 1;
    // ---- stage pair pr -> LDS (bf16); keep packed copies ----
    ushort4_t h[4];
#pragma unroll
    for (int j = 0; j < 4; ++j) h[j] = pack_bf16x4(cur[j]);
    *(ushort4_t*)((char*)&ldsHi[p][0][0] + off0) = h[0];
    *(ushort4_t*)((char*)&ldsHi[p][0][0] + off1) = h[1];
    *(ushort4_t*)((char*)&ldsHi[p][1][0] + off0) = h[2];
    *(ushort4_t*)((char*)&ldsHi[p][1][0] + off1) = h[3];
    // ---- issue pair pr+1 loads (consumed next pair-top: ~1 body slack) ----
    if (pr + 1 < NPAIRS) {
      const int tb = t0 + (pr + 1) * 32;
      cur[0] = *(const f32x4*)(keyN + (size_t)(tb + wv) * CKC + c40);
      cur[1] = *(const f32x4*)(keyN + (size_t)(tb + wv + 8) * CKC + c40);
      cur[2] = *(const f32x4*)(keyN + (size_t)(tb + 16 + wv) * CKC + c40);
      cur[3] = *(const f32x4*)(keyN + (size_t)(tb + 16 + wv + 8) * CKC + c40);
    }
    barrier_lgkm();  // the ONLY barrier per 32 rows; does NOT drain vmcnt

    // ---- 2 tiles: ds_read + MFMA (prio-boosted) + tanh + DPP ----
#pragma unroll
    for (int tl = 0; tl < 2; ++tl) {
      const char* base = (const char*)&ldsHi[p][tl][0];
      // qpb folded into C-init: D = A*B + C with C[i] = qpb_u
      f32x4 acca = {qpb_u, qpb_u, qpb_u, qpb_u};
      f32x4 accb = {0.f, 0.f, 0.f, 0.f};
      __builtin_amdgcn_s_setprio(1);
#pragma unroll
      for (int kt = 0; kt < 4; ++kt) {
        short8 kf = *(const short8*)(base + ((abase + (unsigned)(kt * 64)) ^ axor));
        acca = __builtin_amdgcn_mfma_f32_16x16x32_bf16(kf, bhi[kt], acca, 0, 0, 0);
      }
#pragma unroll
      for (int kt = 4; kt < 8; ++kt) {
        short8 kf = *(const short8*)(base + ((abase + (unsigned)(kt * 64)) ^ axor));
        accb = __builtin_amdgcn_mfma_f32_16x16x32_bf16(kf, bhi[kt], accb, 0, 0, 0);
      }
      __builtin_amdgcn_s_setprio(0);
      float sv[4];
#pragma unroll
      for (int i = 0; i < 4; ++i)
        sv[i] = v_u * fast_tanh(acca[i] + accb[i]);
#pragma unroll
      for (int i = 0; i < 4; ++i) {
        sv[i] = row_shl_add<8>(sv[i]);
        sv[i] = row_shl_add<4>(sv[i]);
        sv[i] = row_shl_add<2>(sv[i]);
        sv[i] = row_shl_add<1>(sv[i]);
      }
      if ((lane & 15) == 0) {
        const int g = lane >> 4;
#pragma unroll
        for (int i = 0; i < 4; ++i) spart_t[p][tl][g * 4 + i][wv] = sv[i];
      }
    }

    // ---- deferred softmax + context for pair pr-1 (spart buf p^1) ----
    if (pr > 0) {
      const int q = p ^ 1;
#pragma unroll
      for (int tl = 0; tl < 2; ++tl) {
        const int rbase = (pr - 1) * 32 + tl * 16;
        const f32x4* sp0 = (const f32x4*)&spart_t[q][tl][wv][0];
        const f32x4* sp1 = (const f32x4*)&spart_t[q][tl][wv + 8][0];
        float st0 = gbuf[rbase + wv] + hsum4(sp0[0] + sp0[1]);
        float st1 = gbuf[rbase + wv + 8] + hsum4(sp1[0] + sp1[1]);
        float w0 = __expf(st0 - FIXED_MAX);
        float w1 = __expf(st1 - FIXED_MAX);
        const ushort4_t pva = pv[tl * 2 + 0];
        const ushort4_t pvb = pv[tl * 2 + 1];
#pragma unroll
        for (int j = 0; j < 4; ++j) {
          acc0[j] += w0 * bf2f(pva[j]);
          acc1[j] += w1 * bf2f(pvb[j]);
        }
        l_acc += w0 + w1;
        if (lane == 0) {  // st0/st1 wave-uniform: this wave owns these rows
          out_align[(size_t)n * T_LEN + t0 + rbase + wv] = st0;
          out_align[(size_t)n * T_LEN + t0 + rbase + wv + 8] = st1;
        }
      }
    }
    // rotate packed rows
#pragma unroll
    for (int j = 0; j < 4; ++j) pv[j] = h[j];
  }

  // ---- epilogue: softmax + context for the last pair ----
  barrier_lgkm();
  {
    const int q = (NPAIRS - 1) & 1;
#pragma unroll
    for (int tl = 0; tl < 2; ++tl) {
      const int rbase = (NPAIRS - 1) * 32 + tl * 16;
      const f32x4* sp0 = (const f32x4*)&spart_t[q][tl][wv][0];
      const f32x4* sp1 = (const f32x4*)&spart_t[q][tl][wv + 8][0];
      float st0 = gbuf[rbase + wv] + hsum4(sp0[0] + sp0[1]);
      float st1 = gbuf[rbase + wv + 8] + hsum4(sp1[0] + sp1[1]);
      float w0 = __expf(st0 - FIXED_MAX);
      float w1 = __expf(st1 - FIXED_MAX);
      const ushort4_t pva = pv[tl * 2 + 0];
      const ushort4_t pvb = pv[tl * 2 + 1];
#pragma unroll
      for (int j = 0; j < 4; ++j) {
        acc0[j] += w0 * bf2f(pva[j]);
        acc1[j] += w1 * bf2f(pvb[j]);
      }
      l_acc += w0 + w1;
      if (lane == 0) {
        out_align[(size_t)n * T_LEN + t0 + rbase + wv] = st0;
        out_align[(size_t)n * T_LEN + t0 + rbase + wv + 8] = st1;
      }
    }
  }

  // ---- cross-wave reduce, write partial {l, ctx[256]} ----
  if (lane == 0) lred[wv] = l_acc;
  {
    f32x4 c4;
#pragma unroll
    for (int j = 0; j < 4; ++j) c4[j] = acc0[j] + acc1[j];
    *(f32x4*)&ctx8[wv][c40] = c4;
  }
  barrier_lgkm();
  float* pb = part + (size_t)bid * PART_STRIDE;
  if (tid == 0) {
    float ls = 0.f;
#pragma unroll
    for (int w2 = 0; w2 < 8; ++w2) ls += lred[w2];
    pb[0] = ls;
  }
  if (tid < 256) {
    float cs = 0.f;
#pragma unroll
    for (int w2 = 0; w2 < 8; ++w2) cs += ctx8[w2][tid];
    pb[2 + tid] = cs;
  }
}

// ---------------------------------------------------------------------------
// Kernel 2: combine per-chunk partials -> context; in-place score -> align.
__global__ void combine_kernel(const float* __restrict__ part,
                               float* __restrict__ out_ctx,
                               float* __restrict__ out_align) {
  __shared__ float lp[NCHUNK];
  const int n = blockIdx.x >> 3;
  const int seg = blockIdx.x & 7;
  const int tid = threadIdx.x;
  if (tid < NCHUNK)
    lp[tid] = part[(size_t)(n * NCHUNK + tid) * PART_STRIDE];
  __syncthreads();
  float lg = 0.f;
#pragma unroll 8
  for (int j = 0; j < NCHUNK; ++j) lg += lp[j];
  const float inv = 1.0f / lg;
  if (seg == 0) {
    float ca = 0.f;
    for (int j = 0; j < NCHUNK; ++j)
      ca += part[(size_t)(n * NCHUNK + j) * PART_STRIDE + 2 + tid];
    out_ctx[n * 256 + tid] = ca * inv;
  }
  const int tb = seg * (T_LEN / 8);
#pragma unroll
  for (int i = 0; i < T_LEN / 8 / 256; ++i) {
    const int t = tb + i * 256 + tid;
    float s = out_align[(size_t)n * T_LEN + t];
    out_align[(size_t)n * T_LEN + t] = __expf(s - FIXED_MAX) * inv;
  }
}

// ---------------------------------------------------------------------------
extern "C" void kernel_launch(void* const* d_in, const int* in_sizes, int n_in,
                              void* d_out, int out_size, void* d_ws, size_t ws_size,
                              hipStream_t stream) {
  const float* query = (const float*)d_in[0];
  const float* key = (const float*)d_in[1];
  const float* w_conv = (const float*)d_in[2];
  const float* w_q = (const float*)d_in[3];
  const float* w_k = (const float*)d_in[4];
  const float* v = (const float*)d_in[5];
  const float* b = (const float*)d_in[6];
  const float* gumbel = (const float*)d_in[7];

  float* out = (float*)d_out;
  float* out_ctx = out;                 // 32*256
  float* out_align = out + NB * CKC;    // 32*8192

  char* ws = (char*)d_ws;
  float* qpb = (float*)ws;                                    // 16 KB
  unsigned short* wkT_hi = (unsigned short*)(ws + 16 * 1024); // 64 KB
  float* part = (float*)(ws + 144 * 1024);                    // 2048*258*4 B

  prep_kernel<<<dim3(NB + CKC), dim3(256), 0, stream>>>(
      query, w_conv, w_q, b, w_k, qpb, wkT_hi);
  fused_attn_kernel<<<dim3(NB * NCHUNK), dim3(512), 0, stream>>>(
      key, gumbel, v, qpb, wkT_hi, part, out_align);
  combine_kernel<<<dim3(NB * 8), dim3(256), 0, stream>>>(part, out_ctx, out_align);
}